// Round 19
// baseline (87.378 us; speedup 1.0000x reference)
//
#include <hip/hip_runtime.h>

#define BB 4096   // batch
#define TT 512    // time steps
#define DD 32     // input dim
#define NL 10     // layers
#define PH 8      // steps per phase
#define PHASES 66 // 528 steps
#define CPB 4     // chains per block (1024 blocks, 1 wave/SIMD)

static constexpr float L2E = 1.4426950408889634f;   // log2(e)
static constexpr float GCL = 26.0f;                 // producer g-clamp (scaled)

typedef float f4 __attribute__((ext_vector_type(4)));
typedef float f2 __attribute__((ext_vector_type(2)));

__device__ __forceinline__ float fexp2(float x) { return __builtin_amdgcn_exp2f(x); }
__device__ __forceinline__ float frcp(float x)  { return __builtin_amdgcn_rcpf(x); }
__device__ __forceinline__ float fmed3(float x, float a, float b) {
    return __builtin_amdgcn_fmed3f(x, a, b);
}

// row_shr:1 within each 16-lane row; row-lane 0 gets 0 (bound_ctrl).
__device__ __forceinline__ float dpp_shr1(float x) {
    int r = __builtin_amdgcn_update_dpp(0, __float_as_int(x), 0x111, 0xF, 0xF, true);
    return __int_as_float(r);
}

template<int CTRL>
__device__ __forceinline__ float dpp_add(float x) {
    return x + __int_as_float(__builtin_amdgcn_update_dpp(
        0, __float_as_int(x), CTRL, 0xF, 0xF, true));
}
#define DPP_XOR1 0xB1   // quad_perm [1,0,3,2]
#define DPP_XOR2 0x4E   // quad_perm [2,3,0,1]
#define DPP_ROR4 0x124  // row_ror:4 cross-quad gather (verified R10)

// ---------------------------------------------------------------------------
// R19 = R18 with the 8-step STEP runs split into 2x unroll-4 sub-loops to
// halve the unrolled I-footprint (I-cache pressure test; jm rotation is
// invariant under the split). Producer/consumer math identical to R18.
// ---------------------------------------------------------------------------
__global__ __launch_bounds__(64) void k_fused(
    const float* __restrict__ x, const float* __restrict__ Wih0,
    const float* __restrict__ Whh0, const float* __restrict__ b0,
    const float* __restrict__ Wihr, const float* __restrict__ Whhr,
    const float* __restrict__ br, float* __restrict__ out)
{
    __shared__ float4 gbuf[2][CPB][PH + 1];   // [slot][chain][step], +1 pad

    const int lane = threadIdx.x & 63;
    const int blk  = blockIdx.x;

    // ---- producer-role constants: per-element transposed weight pairs ----
    const int pg = lane >> 3;               // step-in-phase this lane helps produce
    const int pc = lane & 7;                // float4 chunk of the 32-wide x row
    f2 wt01[4], wt23[4];
#pragma unroll
    for (int e = 0; e < 4; e++) {
        int col = pc * 4 + e;
        wt01[e] = f2{Wih0[0 * DD + col], Wih0[1 * DD + col]};
        wt23[e] = f2{Wih0[2 * DD + col], Wih0[3 * DD + col]};
    }
    const float pb0 = b0[0], pb1 = b0[1], pb2 = b0[2], pb3 = b0[3];

    // ---- consumer-role constants ----
    const int cidx = lane >> 4;             // row = chain-in-block
    const int l = lane & 15;                // 0..9 live layers
    const int chain = blk * CPB + cidx;
    const float sk0 = -L2E, sk1 = -L2E, sk2 = -2.f * L2E, sk3 = -L2E;
    const bool isl0 = (l == 0), isl9 = (l == NL - 1);
    const int li = (l >= 1 && l <= 9) ? (l - 1) : 0;

    float wi0 = 0, wi1 = 0, wi2 = 0, wi3 = 0;
    float wh0, wh1, wh2, wh3;
    float bb0 = 0, bb1 = 0, bb2 = 0, bb3 = 0;
    if (isl0) {
        wh0 = sk0 * Whh0[0]; wh1 = sk1 * Whh0[1];
        wh2 = sk2 * Whh0[2]; wh3 = sk3 * Whh0[3];
    } else {
        const float* pi = Wihr + li * 4;
        const float* ph = Whhr + li * 4;
        const float* pb = br   + li * 4;
        wi0 = sk0 * pi[0]; wi1 = sk1 * pi[1]; wi2 = sk2 * pi[2]; wi3 = sk3 * pi[3];
        wh0 = sk0 * ph[0]; wh1 = sk1 * ph[1]; wh2 = sk2 * ph[2]; wh3 = sk3 * ph[3];
        bb0 = sk0 * pb[0]; bb1 = sk1 * pb[1]; bb2 = sk2 * pb[2]; bb3 = sk3 * pb[3];
    }

    const f2 wi01 = {wi0, wi1}, wi23 = {wi2, wi3};
    const f2 wh01 = {wh0, wh1}, wh23 = {wh2, wh3};

    float* outp = out + (size_t)chain * TT;
    float h = 0.f, cs = 0.f;                // c in natural units
    float o0 = 0.f, o1 = 0.f, o2 = 0.f, o3 = 0.f;

    const float* xb = x + (size_t)blk * CPB * TT * DD;

    f4 VA0, VA1, VA2, VA3, VB0, VB1, VB2, VB3;

    auto LOADV = [&](f4& v0, f4& v1, f4& v2, f4& v3, int p) {
        int t = p * PH + pg; t = t < TT ? t : TT - 1;   // tail clamps (discarded)
        const float* base = xb + (size_t)t * DD + pc * 4;
        v0 = __builtin_nontemporal_load((const f4*)(base + 0 * TT * DD));
        v1 = __builtin_nontemporal_load((const f4*)(base + 1 * TT * DD));
        v2 = __builtin_nontemporal_load((const f4*)(base + 2 * TT * DD));
        v3 = __builtin_nontemporal_load((const f4*)(base + 3 * TT * DD));
    };

    auto PROD1 = [&](const f4 v, int ci, int slot) {    // ci, slot literal at call site
        // packed dual-gate accumulation: 8 v_pk_fma_f32
        f2 a01 = f2{v.x, v.x} * wt01[0];
        f2 a23 = f2{v.x, v.x} * wt23[0];
        a01 = f2{v.y, v.y} * wt01[1] + a01;
        a23 = f2{v.y, v.y} * wt23[1] + a23;
        a01 = f2{v.z, v.z} * wt01[2] + a01;
        a23 = f2{v.z, v.z} * wt23[2] + a23;
        a01 = f2{v.w, v.w} * wt01[3] + a01;
        a23 = f2{v.w, v.w} * wt23[3] + a23;
        float p0 = a01.x, p1 = a01.y, p2 = a23.x, p3 = a23.y;
        p0 = dpp_add<DPP_XOR1>(p0); p1 = dpp_add<DPP_XOR1>(p1);
        p2 = dpp_add<DPP_XOR1>(p2); p3 = dpp_add<DPP_XOR1>(p3);
        p0 = dpp_add<DPP_XOR2>(p0); p1 = dpp_add<DPP_XOR2>(p1);
        p2 = dpp_add<DPP_XOR2>(p2); p3 = dpp_add<DPP_XOR2>(p3);
        p0 = dpp_add<DPP_ROR4>(p0); p1 = dpp_add<DPP_ROR4>(p1);
        p2 = dpp_add<DPP_ROR4>(p2); p3 = dpp_add<DPP_ROR4>(p3);
        if (pc == 0) {
            float4 o;
            o.x = fmed3(-L2E * (p0 + pb0), -GCL, GCL);       // overflow guard
            o.y = fmed3(-L2E * (p1 + pb1), -GCL, GCL);
            o.z = fmed3(-2.f * L2E * (p2 + pb2), -GCL, GCL);
            o.w = fmed3(-L2E * (p3 + pb3), -GCL, GCL);
            gbuf[slot][ci][pg] = o;
        }
    };

    auto READR = [&](float4* R, int slot) {
        if (isl0) {
#pragma unroll
            for (int j = 0; j < PH; j++) R[j] = gbuf[slot][cidx][j];
        }
    };

    auto STEP = [&](float4 g, int s, int jm) {
        int t = s - l;
        bool active = (t >= 0) && (t < TT);

        // pre-fma on h (available now) runs PARALLEL to the dpp:
        f2 h2  = {h, h};
        f2 g01 = {g.x, g.y}, g23 = {g.z, g.w};
        f2 pre01 = h2 * wh01 + g01;               // v_pk_fma_f32
        f2 pre23 = h2 * wh23 + g23;
        float hin = dpp_shr1(h);                  // h_{l-1}(t)
        f2 hin2 = {hin, hin};
        f2 u01 = hin2 * wi01 + pre01;
        f2 u23 = hin2 * wi23 + pre23;

        float E0 = fexp2(u01.x), E1 = fexp2(u01.y);
        float E2 = fexp2(u23.x), E3 = fexp2(u23.y);
        float A0 = 1.f + E0, A1 = 1.f + E1, A2 = 1.f + E2, A3 = 1.f + E3;
        float M1 = A0 * A2;
        float M2 = M1 * A1;
        float R  = frcp(M2);                      // one rcp for c-update
        float SA = (1.f - E2) * A1;
        float N  = fmaf(cs, M1, SA);
        float cn = N * R;                         // c_new
        float mc = fmed3(cn, -3.2f, 3.2f);        // Pade validity window
        float x2 = mc * mc;
        f2 x22 = {x2, x2};
        f2 c1 = {1.0f, 15.f}, c2v = {105.f, 420.f}, c3 = {945.f, 945.f};
        f2 npd = x22 * (x22 * c1 + c2v) + c3;     // {pn, pd} packed
        float RQ = frcp(npd.y * A3);              // tanh-den + o-gate fused
        float hn = (mc * npd.x) * RQ;             // h_new = o * tanh(c_new)

        if (active) { cs = cn; h = hn; }

        if (jm == 1) o0 = hn;
        else if (jm == 2) o1 = hn;
        else if (jm == 3) o2 = hn;
        else o3 = hn;                              // jm == 0
        if (jm == 0 && s >= 12 && s <= 520 && isl9) {
            f4 v;
            v.x = 60.f * frcp(1.f + fexp2(-L2E * o0));
            v.y = 60.f * frcp(1.f + fexp2(-L2E * o1));
            v.z = 60.f * frcp(1.f + fexp2(-L2E * o2));
            v.w = 60.f * frcp(1.f + fexp2(-L2E * o3));
            __builtin_nontemporal_store(v, (f4*)(outp + (s - 12)));
        }
    };

    // 4-step runs keep the jm rotation intact while halving unrolled code.
    auto RUN4 = [&](float4* R, int base, int off) {
#pragma unroll
        for (int j = 0; j < 4; j++) STEP(R[off + j], base + off + j, j & 3);
    };
    auto RUN8 = [&](float4* R, int base) {
        for (int jj = 0; jj < PH; jj += 4) RUN4(R, base, jj);   // NOT unrolled
    };

    float4 RA[PH], RB[PH];
    float4 bbv = make_float4(bb0, bb1, bb2, bb3);
#pragma unroll
    for (int i = 0; i < PH; i++) { RA[i] = bbv; RB[i] = bbv; }

    // prologue: VA<-ph0, VB<-ph1; produce ph0; regs<-ph0; VA<-ph2
    LOADV(VA0, VA1, VA2, VA3, 0);
    LOADV(VB0, VB1, VB2, VB3, 1);
    PROD1(VA0, 0, 0); PROD1(VA1, 1, 0); PROD1(VA2, 2, 0); PROD1(VA3, 3, 0);
    READR(RA, 0);
    LOADV(VA0, VA1, VA2, VA3, 2);

    // steady state: at top RA=regs(ph p), VB=x(ph p+1), VA=x(ph p+2)
    for (int p = 0; p < PHASES; p += 2) {
        PROD1(VB0, 0, 1); PROD1(VB1, 1, 1); PROD1(VB2, 2, 1); PROD1(VB3, 3, 1);
        RUN8(RA, p * PH);
        READR(RB, 1);                                  // regs <- ph p+1
        LOADV(VB0, VB1, VB2, VB3, p + 3);

        PROD1(VA0, 0, 0); PROD1(VA1, 1, 0); PROD1(VA2, 2, 0); PROD1(VA3, 3, 0);
        RUN8(RB, (p + 1) * PH);
        READR(RA, 0);                                  // regs <- ph p+2
        LOADV(VA0, VA1, VA2, VA3, p + 4);
    }
}

extern "C" void kernel_launch(void* const* d_in, const int* in_sizes, int n_in,
                              void* d_out, int out_size, void* d_ws, size_t ws_size,
                              hipStream_t stream)
{
    const float* x    = (const float*)d_in[0];
    const float* Wih0 = (const float*)d_in[1];
    const float* Whh0 = (const float*)d_in[2];
    const float* b0   = (const float*)d_in[3];
    const float* Wihr = (const float*)d_in[4];
    const float* Whhr = (const float*)d_in[5];
    const float* br   = (const float*)d_in[6];
    float* out = (float*)d_out;

    k_fused<<<BB / CPB, 64, 0, stream>>>(x, Wih0, Whh0, b0, Wihr, Whhr, br, out);
}

// Round 20
// 84.168 us; speedup vs baseline: 1.0381x; 1.0381x over previous
//
#include <hip/hip_runtime.h>

#define BB 4096   // batch
#define TT 512    // time steps
#define DD 32     // input dim
#define NL 10     // layers
#define PH 8      // steps per phase
#define PHASES 66 // 528 steps
#define CPB 4     // chains per block (1024 blocks, 1 wave/SIMD)

static constexpr float L2E = 1.4426950408889634f;   // log2(e)
static constexpr float GCL = 26.0f;                 // producer g-clamp (scaled)

typedef float f4 __attribute__((ext_vector_type(4)));
typedef float f2 __attribute__((ext_vector_type(2)));

__device__ __forceinline__ float fexp2(float x) { return __builtin_amdgcn_exp2f(x); }
__device__ __forceinline__ float frcp(float x)  { return __builtin_amdgcn_rcpf(x); }
__device__ __forceinline__ float fmed3(float x, float a, float b) {
    return __builtin_amdgcn_fmed3f(x, a, b);
}

// row_shr:1 within each 16-lane row; row-lane 0 gets 0 (bound_ctrl).
__device__ __forceinline__ float dpp_shr1(float x) {
    int r = __builtin_amdgcn_update_dpp(0, __float_as_int(x), 0x111, 0xF, 0xF, true);
    return __int_as_float(r);
}

template<int CTRL>
__device__ __forceinline__ float dpp_add(float x) {
    return x + __int_as_float(__builtin_amdgcn_update_dpp(
        0, __float_as_int(x), CTRL, 0xF, 0xF, true));
}
#define DPP_XOR1 0xB1   // quad_perm [1,0,3,2]
#define DPP_XOR2 0x4E   // quad_perm [2,3,0,1]
#define DPP_ROR4 0x124  // row_ror:4 cross-quad gather (verified R10)

// ---------------------------------------------------------------------------
// R20 = R18 verbatim (best measured: 84.4 us). Single-wave fused
// producer/consumer: packed producer dots (v_pk_fma_f32, per-element
// transposed weights) + DPP reduce, skewed 10-layer pipeline with DPP
// row_shr:1 handoff, combined-rcp + Pade tanh STEP, nt loads and stores.
// ---------------------------------------------------------------------------
__global__ __launch_bounds__(64) void k_fused(
    const float* __restrict__ x, const float* __restrict__ Wih0,
    const float* __restrict__ Whh0, const float* __restrict__ b0,
    const float* __restrict__ Wihr, const float* __restrict__ Whhr,
    const float* __restrict__ br, float* __restrict__ out)
{
    __shared__ float4 gbuf[2][CPB][PH + 1];   // [slot][chain][step], +1 pad

    const int lane = threadIdx.x & 63;
    const int blk  = blockIdx.x;

    // ---- producer-role constants: per-element transposed weight pairs ----
    const int pg = lane >> 3;               // step-in-phase this lane helps produce
    const int pc = lane & 7;                // float4 chunk of the 32-wide x row
    f2 wt01[4], wt23[4];
#pragma unroll
    for (int e = 0; e < 4; e++) {
        int col = pc * 4 + e;
        wt01[e] = f2{Wih0[0 * DD + col], Wih0[1 * DD + col]};
        wt23[e] = f2{Wih0[2 * DD + col], Wih0[3 * DD + col]};
    }
    const float pb0 = b0[0], pb1 = b0[1], pb2 = b0[2], pb3 = b0[3];

    // ---- consumer-role constants ----
    const int cidx = lane >> 4;             // row = chain-in-block
    const int l = lane & 15;                // 0..9 live layers
    const int chain = blk * CPB + cidx;
    const float sk0 = -L2E, sk1 = -L2E, sk2 = -2.f * L2E, sk3 = -L2E;
    const bool isl0 = (l == 0), isl9 = (l == NL - 1);
    const int li = (l >= 1 && l <= 9) ? (l - 1) : 0;

    float wi0 = 0, wi1 = 0, wi2 = 0, wi3 = 0;
    float wh0, wh1, wh2, wh3;
    float bb0 = 0, bb1 = 0, bb2 = 0, bb3 = 0;
    if (isl0) {
        wh0 = sk0 * Whh0[0]; wh1 = sk1 * Whh0[1];
        wh2 = sk2 * Whh0[2]; wh3 = sk3 * Whh0[3];
    } else {
        const float* pi = Wihr + li * 4;
        const float* ph = Whhr + li * 4;
        const float* pb = br   + li * 4;
        wi0 = sk0 * pi[0]; wi1 = sk1 * pi[1]; wi2 = sk2 * pi[2]; wi3 = sk3 * pi[3];
        wh0 = sk0 * ph[0]; wh1 = sk1 * ph[1]; wh2 = sk2 * ph[2]; wh3 = sk3 * ph[3];
        bb0 = sk0 * pb[0]; bb1 = sk1 * pb[1]; bb2 = sk2 * pb[2]; bb3 = sk3 * pb[3];
    }

    const f2 wi01 = {wi0, wi1}, wi23 = {wi2, wi3};
    const f2 wh01 = {wh0, wh1}, wh23 = {wh2, wh3};

    float* outp = out + (size_t)chain * TT;
    float h = 0.f, cs = 0.f;                // c in natural units
    float o0 = 0.f, o1 = 0.f, o2 = 0.f, o3 = 0.f;

    const float* xb = x + (size_t)blk * CPB * TT * DD;

    f4 VA0, VA1, VA2, VA3, VB0, VB1, VB2, VB3;

    auto LOADV = [&](f4& v0, f4& v1, f4& v2, f4& v3, int p) {
        int t = p * PH + pg; t = t < TT ? t : TT - 1;   // tail clamps (discarded)
        const float* base = xb + (size_t)t * DD + pc * 4;
        v0 = __builtin_nontemporal_load((const f4*)(base + 0 * TT * DD));
        v1 = __builtin_nontemporal_load((const f4*)(base + 1 * TT * DD));
        v2 = __builtin_nontemporal_load((const f4*)(base + 2 * TT * DD));
        v3 = __builtin_nontemporal_load((const f4*)(base + 3 * TT * DD));
    };

    auto PROD1 = [&](const f4 v, int ci, int slot) {    // ci, slot literal at call site
        // packed dual-gate accumulation: 8 v_pk_fma_f32
        f2 a01 = f2{v.x, v.x} * wt01[0];
        f2 a23 = f2{v.x, v.x} * wt23[0];
        a01 = f2{v.y, v.y} * wt01[1] + a01;
        a23 = f2{v.y, v.y} * wt23[1] + a23;
        a01 = f2{v.z, v.z} * wt01[2] + a01;
        a23 = f2{v.z, v.z} * wt23[2] + a23;
        a01 = f2{v.w, v.w} * wt01[3] + a01;
        a23 = f2{v.w, v.w} * wt23[3] + a23;
        float p0 = a01.x, p1 = a01.y, p2 = a23.x, p3 = a23.y;
        p0 = dpp_add<DPP_XOR1>(p0); p1 = dpp_add<DPP_XOR1>(p1);
        p2 = dpp_add<DPP_XOR1>(p2); p3 = dpp_add<DPP_XOR1>(p3);
        p0 = dpp_add<DPP_XOR2>(p0); p1 = dpp_add<DPP_XOR2>(p1);
        p2 = dpp_add<DPP_XOR2>(p2); p3 = dpp_add<DPP_XOR2>(p3);
        p0 = dpp_add<DPP_ROR4>(p0); p1 = dpp_add<DPP_ROR4>(p1);
        p2 = dpp_add<DPP_ROR4>(p2); p3 = dpp_add<DPP_ROR4>(p3);
        if (pc == 0) {
            float4 o;
            o.x = fmed3(-L2E * (p0 + pb0), -GCL, GCL);       // overflow guard
            o.y = fmed3(-L2E * (p1 + pb1), -GCL, GCL);
            o.z = fmed3(-2.f * L2E * (p2 + pb2), -GCL, GCL);
            o.w = fmed3(-L2E * (p3 + pb3), -GCL, GCL);
            gbuf[slot][ci][pg] = o;
        }
    };

    auto READR = [&](float4* R, int slot) {
        if (isl0) {
#pragma unroll
            for (int j = 0; j < PH; j++) R[j] = gbuf[slot][cidx][j];
        }
    };

    auto STEP = [&](float4 g, int s, int jm) {
        int t = s - l;
        bool active = (t >= 0) && (t < TT);

        // pre-fma on h (available now) runs PARALLEL to the dpp:
        f2 h2  = {h, h};
        f2 g01 = {g.x, g.y}, g23 = {g.z, g.w};
        f2 pre01 = h2 * wh01 + g01;               // v_pk_fma_f32
        f2 pre23 = h2 * wh23 + g23;
        float hin = dpp_shr1(h);                  // h_{l-1}(t)
        f2 hin2 = {hin, hin};
        f2 u01 = hin2 * wi01 + pre01;
        f2 u23 = hin2 * wi23 + pre23;

        float E0 = fexp2(u01.x), E1 = fexp2(u01.y);
        float E2 = fexp2(u23.x), E3 = fexp2(u23.y);
        float A0 = 1.f + E0, A1 = 1.f + E1, A2 = 1.f + E2, A3 = 1.f + E3;
        float M1 = A0 * A2;
        float M2 = M1 * A1;
        float R  = frcp(M2);                      // one rcp for c-update
        float SA = (1.f - E2) * A1;
        float N  = fmaf(cs, M1, SA);
        float cn = N * R;                         // c_new
        float mc = fmed3(cn, -3.2f, 3.2f);        // Pade validity window
        float x2 = mc * mc;
        f2 x22 = {x2, x2};
        f2 c1 = {1.0f, 15.f}, c2v = {105.f, 420.f}, c3 = {945.f, 945.f};
        f2 npd = x22 * (x22 * c1 + c2v) + c3;     // {pn, pd} packed
        float RQ = frcp(npd.y * A3);              // tanh-den + o-gate fused
        float hn = (mc * npd.x) * RQ;             // h_new = o * tanh(c_new)

        if (active) { cs = cn; h = hn; }

        if (jm == 1) o0 = hn;
        else if (jm == 2) o1 = hn;
        else if (jm == 3) o2 = hn;
        else o3 = hn;                              // jm == 0
        if (jm == 0 && s >= 12 && s <= 520 && isl9) {
            f4 v;
            v.x = 60.f * frcp(1.f + fexp2(-L2E * o0));
            v.y = 60.f * frcp(1.f + fexp2(-L2E * o1));
            v.z = 60.f * frcp(1.f + fexp2(-L2E * o2));
            v.w = 60.f * frcp(1.f + fexp2(-L2E * o3));
            __builtin_nontemporal_store(v, (f4*)(outp + (s - 12)));
        }
    };

    float4 RA[PH], RB[PH];
    float4 bbv = make_float4(bb0, bb1, bb2, bb3);
#pragma unroll
    for (int i = 0; i < PH; i++) { RA[i] = bbv; RB[i] = bbv; }

    // prologue: VA<-ph0, VB<-ph1; produce ph0; regs<-ph0; VA<-ph2
    LOADV(VA0, VA1, VA2, VA3, 0);
    LOADV(VB0, VB1, VB2, VB3, 1);
    PROD1(VA0, 0, 0); PROD1(VA1, 1, 0); PROD1(VA2, 2, 0); PROD1(VA3, 3, 0);
    READR(RA, 0);
    LOADV(VA0, VA1, VA2, VA3, 2);

    // steady state: at top RA=regs(ph p), VB=x(ph p+1), VA=x(ph p+2)
    for (int p = 0; p < PHASES; p += 2) {
        PROD1(VB0, 0, 1); PROD1(VB1, 1, 1); PROD1(VB2, 2, 1); PROD1(VB3, 3, 1);
#pragma unroll
        for (int j = 0; j < PH; j++) STEP(RA[j], p * PH + j, j & 3);
        READR(RB, 1);                                  // regs <- ph p+1
        LOADV(VB0, VB1, VB2, VB3, p + 3);

        PROD1(VA0, 0, 0); PROD1(VA1, 1, 0); PROD1(VA2, 2, 0); PROD1(VA3, 3, 0);
#pragma unroll
        for (int j = 0; j < PH; j++) STEP(RB[j], (p + 1) * PH + j, j & 3);
        READR(RA, 0);                                  // regs <- ph p+2
        LOADV(VA0, VA1, VA2, VA3, p + 4);
    }
}

extern "C" void kernel_launch(void* const* d_in, const int* in_sizes, int n_in,
                              void* d_out, int out_size, void* d_ws, size_t ws_size,
                              hipStream_t stream)
{
    const float* x    = (const float*)d_in[0];
    const float* Wih0 = (const float*)d_in[1];
    const float* Whh0 = (const float*)d_in[2];
    const float* b0   = (const float*)d_in[3];
    const float* Wihr = (const float*)d_in[4];
    const float* Whhr = (const float*)d_in[5];
    const float* br   = (const float*)d_in[6];
    float* out = (float*)d_out;

    k_fused<<<BB / CPB, 64, 0, stream>>>(x, Wih0, Whh0, b0, Wihr, Whhr, br, out);
}